// Round 10
// baseline (1538.215 us; speedup 1.0000x reference)
//
#include <hip/hip_runtime.h>
#include <hip/hip_bf16.h>

typedef __hip_bfloat16 hipbf16;

#define H 128
#define NLAYERS 4
#define LN_EPS 1e-5f

typedef __bf16 bf16x8 __attribute__((ext_vector_type(8)));
typedef unsigned short ushort8 __attribute__((ext_vector_type(8)));
typedef float floatx16 __attribute__((ext_vector_type(16)));

union frag_u { ushort8 u; bf16x8 b; };

__device__ __forceinline__ float silu(float x) {
    return x * __builtin_amdgcn_rcpf(1.f + __expf(-x));
}
__device__ __forceinline__ float b2f_bits(unsigned short u) { return __uint_as_float(((unsigned)u) << 16); }
__device__ __forceinline__ unsigned short f2b(float f) {
    unsigned u = __float_as_uint(f);
    unsigned r = ((u >> 16) & 1u) + 0x7fffu;
    return (unsigned short)((u + r) >> 16);
}

// ---------------- dtype detection (wire fp32 vs bf16) ----------------
__global__ void detect_kernel(const unsigned short* __restrict__ p, int nHalf,
                              int* __restrict__ flag) {
    int t = threadIdx.x;
    int bad = 0;
    for (int i = t; i < nHalf; i += 64) {
        unsigned short u = p[i];
        int e = (u >> 7) & 0xFF;
        if (e >= 0x8E) bad = 1;
    }
    unsigned long long m = __ballot(bad != 0);
    if (t == 0) *flag = (m != 0ULL) ? 1 : 0;   // 1 => fp32 wire
}

__global__ void conv_kernel(const void* __restrict__ src, float* __restrict__ dst,
                            int n, const int* __restrict__ flag) {
    int i = blockIdx.x * blockDim.x + threadIdx.x;
    if (i >= n) return;
    if (*flag) dst[i] = ((const float*)src)[i];
    else       dst[i] = b2f_bits(((const unsigned short*)src)[i]);
}

// Pack W[K x 128] (fp32) into MFMA B-fragment order
__global__ void pack_kernel(const float* __restrict__ W, unsigned short* __restrict__ blob,
                            int ksteps) {
    int idx = blockIdx.x * 256 + threadIdx.x;
    if (idx >= ksteps * 2048) return;
    int j  = idx & 7;
    int L  = (idx >> 3) & 63;
    int nt = (idx >> 9) & 3;
    int ks = idx >> 11;
    int k = ks * 16 + (L >> 5) * 8 + j;
    int n = nt * 32 + (L & 31);
    blob[idx] = f2b(W[k * H + n]);
}

__global__ void embed_kernel(const int* __restrict__ z, const float* __restrict__ emb,
                             float* __restrict__ h, unsigned short* __restrict__ hb, int n) {
    int idx = blockIdx.x * blockDim.x + threadIdx.x;
    if (idx >= n * H) return;
    int i = idx >> 7, j = idx & 127;
    float v = emb[z[i] * H + j];
    h[idx] = v;
    hb[idx] = f2b(v);
}

// ---------------- CSR build (counting sort by destination row) ----------------
__global__ void hist_kernel(const int* __restrict__ row, int* __restrict__ cnt, int nE) {
    int i = blockIdx.x * blockDim.x + threadIdx.x;
    if (i < nE) atomicAdd(&cnt[row[i]], 1);
}

__global__ __launch_bounds__(1024) void scan_kernel(const int* __restrict__ cnt,
                                                    int* __restrict__ rptr,
                                                    int* __restrict__ cur, int nN) {
    __shared__ int wsum[17];
    __shared__ int s_carry;
    int t = threadIdx.x;
    if (t == 0) s_carry = 0;
    __syncthreads();
    for (int base = 0; base < nN; base += 1024) {
        int i = base + t;
        int v = (i < nN) ? cnt[i] : 0;
        int x = v;
        #pragma unroll
        for (int off = 1; off < 64; off <<= 1) {
            int y = __shfl_up(x, off);
            if ((t & 63) >= off) x += y;
        }
        if ((t & 63) == 63) wsum[t >> 6] = x;
        __syncthreads();
        if (t == 0) {
            int s = 0;
            #pragma unroll
            for (int w = 0; w < 16; ++w) { int tmp = wsum[w]; wsum[w] = s; s += tmp; }
            wsum[16] = s;
        }
        __syncthreads();
        int cin = s_carry;
        int excl = cin + wsum[t >> 6] + (x - v);
        if (i < nN) { rptr[i] = excl; cur[i] = excl; }
        __syncthreads();
        if (t == 0) s_carry = cin + wsum[16];
        __syncthreads();
    }
    if (t == 0) rptr[nN] = s_carry;
}

__global__ void scatter_kernel(const int* __restrict__ row, const int* __restrict__ col,
                               const float* __restrict__ pos,
                               int* __restrict__ cur,
                               int* __restrict__ rowsS, int* __restrict__ colsS,
                               float* __restrict__ d2S, int nE) {
    int e = blockIdx.x * blockDim.x + threadIdx.x;
    if (e >= nE) return;
    int r = row[e], c = col[e];
    int p = atomicAdd(&cur[r], 1);
    rowsS[p] = r;
    colsS[p] = c;
    float dx = pos[r * 3 + 0] - pos[c * 3 + 0];
    float dy = pos[r * 3 + 1] - pos[c * 3 + 1];
    float dz = pos[r * 3 + 2] - pos[c * 3 + 2];
    d2S[p] = dx * dx + dy * dy + dz * dz;
}

// ---------------- edge MLP: wave-independent 32-edge tiles, NO barriers ------
// Each wave owns a 32-edge M-tile with full N=128. A-fragments are loaded
// DIRECTLY from global (lane (lm,lh) needs exactly 16B of hb[node]), so no
// gather->LDS->ds_read round trip and no __syncthreads. LDS only for the
// GEMM1->GEMM2 transform, private per wave (in-order DS pipe within a wave).
__global__ __launch_bounds__(256, 4) void edge_wave(
    const unsigned short* __restrict__ hb,
    const int* __restrict__ rowsS, const int* __restrict__ colsS,
    const float* __restrict__ d2S,
    const unsigned short* __restrict__ pb1, const float* __restrict__ b1,
    const float* __restrict__ w1last,
    const unsigned short* __restrict__ pb2, const float* __restrict__ b2,
    float* __restrict__ agg, int nE)
{
    __shared__ __align__(16) unsigned short sT[4][32 * 136];

    const int t = threadIdx.x;
    const int wv = t >> 6, lane = t & 63;
    const int lm = lane & 31, lh = lane >> 5;
    const int base = blockIdx.x * 128 + wv * 32;
    const int p = base + lm;
    const bool valid = p < nE;
    const int pc = valid ? p : (nE - 1);

    const int nrow = rowsS[pc];
    const int ncol = colsS[pc];
    const float dd = d2S[pc];
    const int ptag = valid ? nrow : -1;   // row tag for compaction (-1 = skip)

    const unsigned short* rowp = hb + (size_t)nrow * H + lh * 8;
    const unsigned short* colp = hb + (size_t)ncol * H + lh * 8;

    // GEMM1: [32,256] @ [256,128], A-frags straight from global
    floatx16 a0 = {}, a1 = {}, a2 = {}, a3 = {};
    #pragma unroll
    for (int ks = 0; ks < 16; ++ks) {
        frag_u a;
        a.u = (ks < 8) ? *(const ushort8*)(rowp + ks * 16)
                       : *(const ushort8*)(colp + (ks - 8) * 16);
        frag_u f0, f1, f2, f3;
        f0.u = *(const ushort8*)(pb1 + (size_t)((ks * 4 + 0) * 64 + lane) * 8);
        f1.u = *(const ushort8*)(pb1 + (size_t)((ks * 4 + 1) * 64 + lane) * 8);
        f2.u = *(const ushort8*)(pb1 + (size_t)((ks * 4 + 2) * 64 + lane) * 8);
        f3.u = *(const ushort8*)(pb1 + (size_t)((ks * 4 + 3) * 64 + lane) * 8);
        a0 = __builtin_amdgcn_mfma_f32_32x32x16_bf16(a.b, f0.b, a0, 0, 0, 0);
        a1 = __builtin_amdgcn_mfma_f32_32x32x16_bf16(a.b, f1.b, a1, 0, 0, 0);
        a2 = __builtin_amdgcn_mfma_f32_32x32x16_bf16(a.b, f2.b, a2, 0, 0, 0);
        a3 = __builtin_amdgcn_mfma_f32_32x32x16_bf16(a.b, f3.b, a3, 0, 0, 0);
    }

    // epilogue 1: bias + d2*W1last (d2 of row m via shfl), silu -> own sT
    unsigned short* myT = &sT[wv][0];
    {
        float bA0 = b1[lm], bA1 = b1[32 + lm], bA2 = b1[64 + lm], bA3 = b1[96 + lm];
        float wA0 = w1last[lm], wA1 = w1last[32 + lm], wA2 = w1last[64 + lm], wA3 = w1last[96 + lm];
        #pragma unroll
        for (int r = 0; r < 16; ++r) {
            int m = (r & 3) + 8 * (r >> 2) + 4 * lh;
            float dm = __shfl(dd, m);
            myT[m * 136 + lm]      = f2b(silu(a0[r] + bA0 + dm * wA0));
            myT[m * 136 + 32 + lm] = f2b(silu(a1[r] + bA1 + dm * wA1));
            myT[m * 136 + 64 + lm] = f2b(silu(a2[r] + bA2 + dm * wA2));
            myT[m * 136 + 96 + lm] = f2b(silu(a3[r] + bA3 + dm * wA3));
        }
    }
    __asm__ volatile("s_waitcnt lgkmcnt(0)" ::: "memory");  // wave-local DS drain

    // GEMM2: [32,128] @ [128,128]
    floatx16 c0 = {}, c1 = {}, c2 = {}, c3 = {};
    const unsigned short* A2 = myT + lm * 136 + lh * 8;
    #pragma unroll
    for (int ks = 0; ks < 8; ++ks) {
        frag_u a, f0, f1, f2, f3;
        a.u  = *(const ushort8*)(A2 + ks * 16);
        f0.u = *(const ushort8*)(pb2 + (size_t)((ks * 4 + 0) * 64 + lane) * 8);
        f1.u = *(const ushort8*)(pb2 + (size_t)((ks * 4 + 1) * 64 + lane) * 8);
        f2.u = *(const ushort8*)(pb2 + (size_t)((ks * 4 + 2) * 64 + lane) * 8);
        f3.u = *(const ushort8*)(pb2 + (size_t)((ks * 4 + 3) * 64 + lane) * 8);
        c0 = __builtin_amdgcn_mfma_f32_32x32x16_bf16(a.b, f0.b, c0, 0, 0, 0);
        c1 = __builtin_amdgcn_mfma_f32_32x32x16_bf16(a.b, f1.b, c1, 0, 0, 0);
        c2 = __builtin_amdgcn_mfma_f32_32x32x16_bf16(a.b, f2.b, c2, 0, 0, 0);
        c3 = __builtin_amdgcn_mfma_f32_32x32x16_bf16(a.b, f3.b, c3, 0, 0, 0);
    }

    // epilogue 2: silu + register run-compaction (row tags via shfl)
    {
        float bA0 = b2[lm], bA1 = b2[32 + lm], bA2 = b2[64 + lm], bA3 = b2[96 + lm];
        #pragma unroll
        for (int g = 0; g < 4; ++g) {
            const int m0 = 4 * lh + 8 * g;
            int prow = __shfl(ptag, m0);
            float s0 = silu(c0[g * 4] + bA0);
            float s1 = silu(c1[g * 4] + bA1);
            float s2 = silu(c2[g * 4] + bA2);
            float s3 = silu(c3[g * 4] + bA3);
            #pragma unroll
            for (int k = 1; k < 4; ++k) {
                int rw = __shfl(ptag, m0 + k);
                float u0 = silu(c0[g * 4 + k] + bA0);
                float u1 = silu(c1[g * 4 + k] + bA1);
                float u2 = silu(c2[g * 4 + k] + bA2);
                float u3 = silu(c3[g * 4 + k] + bA3);
                if (rw == prow) {
                    s0 += u0; s1 += u1; s2 += u2; s3 += u3;
                } else {
                    if (prow >= 0) {
                        float* dst = agg + (size_t)prow * H + lm;
                        atomicAdd(dst,      s0);
                        atomicAdd(dst + 32, s1);
                        atomicAdd(dst + 64, s2);
                        atomicAdd(dst + 96, s3);
                    }
                    prow = rw; s0 = u0; s1 = u1; s2 = u2; s3 = u3;
                }
            }
            if (prow >= 0) {
                float* dst = agg + (size_t)prow * H + lm;
                atomicAdd(dst,      s0);
                atomicAdd(dst + 32, s1);
                atomicAdd(dst + 64, s2);
                atomicAdd(dst + 96, s3);
            }
        }
    }
}

// ---------------- node MLP: same wave-independent structure ----------------
__global__ __launch_bounds__(256, 4) void node_wave(
    const unsigned short* __restrict__ hb,
    const float* __restrict__ aggf,
    const unsigned short* __restrict__ pn1, const float* __restrict__ b1,
    const unsigned short* __restrict__ pn2, const float* __restrict__ b2,
    float* __restrict__ hnew, int nN)
{
    __shared__ __align__(16) unsigned short sT[4][32 * 136];

    const int t = threadIdx.x;
    const int wv = t >> 6, lane = t & 63;
    const int lm = lane & 31, lh = lane >> 5;
    const int base = blockIdx.x * 128 + wv * 32;
    const int node = min(base + lm, nN - 1);

    const unsigned short* hp = hb + (size_t)node * H + lh * 8;
    const float* ap = aggf + (size_t)node * H + lh * 8;

    floatx16 a0 = {}, a1 = {}, a2 = {}, a3 = {};
    #pragma unroll
    for (int ks = 0; ks < 16; ++ks) {
        frag_u a;
        if (ks < 8) {
            a.u = *(const ushort8*)(hp + ks * 16);
        } else {
            float4 x = *(const float4*)(ap + (ks - 8) * 16);
            float4 y = *(const float4*)(ap + (ks - 8) * 16 + 4);
            a.u[0] = f2b(x.x); a.u[1] = f2b(x.y); a.u[2] = f2b(x.z); a.u[3] = f2b(x.w);
            a.u[4] = f2b(y.x); a.u[5] = f2b(y.y); a.u[6] = f2b(y.z); a.u[7] = f2b(y.w);
        }
        frag_u f0, f1, f2, f3;
        f0.u = *(const ushort8*)(pn1 + (size_t)((ks * 4 + 0) * 64 + lane) * 8);
        f1.u = *(const ushort8*)(pn1 + (size_t)((ks * 4 + 1) * 64 + lane) * 8);
        f2.u = *(const ushort8*)(pn1 + (size_t)((ks * 4 + 2) * 64 + lane) * 8);
        f3.u = *(const ushort8*)(pn1 + (size_t)((ks * 4 + 3) * 64 + lane) * 8);
        a0 = __builtin_amdgcn_mfma_f32_32x32x16_bf16(a.b, f0.b, a0, 0, 0, 0);
        a1 = __builtin_amdgcn_mfma_f32_32x32x16_bf16(a.b, f1.b, a1, 0, 0, 0);
        a2 = __builtin_amdgcn_mfma_f32_32x32x16_bf16(a.b, f2.b, a2, 0, 0, 0);
        a3 = __builtin_amdgcn_mfma_f32_32x32x16_bf16(a.b, f3.b, a3, 0, 0, 0);
    }

    unsigned short* myT = &sT[wv][0];
    {
        float bA0 = b1[lm], bA1 = b1[32 + lm], bA2 = b1[64 + lm], bA3 = b1[96 + lm];
        #pragma unroll
        for (int r = 0; r < 16; ++r) {
            int m = (r & 3) + 8 * (r >> 2) + 4 * lh;
            myT[m * 136 + lm]      = f2b(silu(a0[r] + bA0));
            myT[m * 136 + 32 + lm] = f2b(silu(a1[r] + bA1));
            myT[m * 136 + 64 + lm] = f2b(silu(a2[r] + bA2));
            myT[m * 136 + 96 + lm] = f2b(silu(a3[r] + bA3));
        }
    }
    __asm__ volatile("s_waitcnt lgkmcnt(0)" ::: "memory");

    floatx16 c0 = {}, c1 = {}, c2 = {}, c3 = {};
    const unsigned short* A2 = myT + lm * 136 + lh * 8;
    #pragma unroll
    for (int ks = 0; ks < 8; ++ks) {
        frag_u a, f0, f1, f2, f3;
        a.u  = *(const ushort8*)(A2 + ks * 16);
        f0.u = *(const ushort8*)(pn2 + (size_t)((ks * 4 + 0) * 64 + lane) * 8);
        f1.u = *(const ushort8*)(pn2 + (size_t)((ks * 4 + 1) * 64 + lane) * 8);
        f2.u = *(const ushort8*)(pn2 + (size_t)((ks * 4 + 2) * 64 + lane) * 8);
        f3.u = *(const ushort8*)(pn2 + (size_t)((ks * 4 + 3) * 64 + lane) * 8);
        c0 = __builtin_amdgcn_mfma_f32_32x32x16_bf16(a.b, f0.b, c0, 0, 0, 0);
        c1 = __builtin_amdgcn_mfma_f32_32x32x16_bf16(a.b, f1.b, c1, 0, 0, 0);
        c2 = __builtin_amdgcn_mfma_f32_32x32x16_bf16(a.b, f2.b, c2, 0, 0, 0);
        c3 = __builtin_amdgcn_mfma_f32_32x32x16_bf16(a.b, f3.b, c3, 0, 0, 0);
    }
    {
        float bA0 = b2[lm], bA1 = b2[32 + lm], bA2 = b2[64 + lm], bA3 = b2[96 + lm];
        #pragma unroll
        for (int r = 0; r < 16; ++r) {
            int m = (r & 3) + 8 * (r >> 2) + 4 * lh;
            int nd = base + m;
            if (nd < nN) {
                float* dst = hnew + (size_t)nd * H + lm;
                dst[0]  = c0[r] + bA0;
                dst[32] = c1[r] + bA1;
                dst[64] = c2[r] + bA2;
                dst[96] = c3[r] + bA3;
            }
        }
    }
}

// residual + layernorm; writes fp32 h and bf16 mirror
__global__ __launch_bounds__(256) void ln_kernel(
    float* __restrict__ h, unsigned short* __restrict__ hb,
    const float* __restrict__ hnew,
    const float* __restrict__ G, const float* __restrict__ B, int nN)
{
    __shared__ float rs[4], rq[4];
    int t = threadIdx.x;
    int local = t >> 7, j = t & 127;
    int i = blockIdx.x * 2 + local;
    float v = 0.f;
    if (i < nN) v = h[(size_t)i * H + j] + hnew[(size_t)i * H + j];
    float s = v, q = v * v;
    #pragma unroll
    for (int off = 32; off > 0; off >>= 1) {
        s += __shfl_down(s, off);
        q += __shfl_down(q, off);
    }
    int w = t >> 6;
    if ((t & 63) == 0) { rs[w] = s; rq[w] = q; }
    __syncthreads();
    int w0 = local * 2;
    float S = rs[w0] + rs[w0 + 1], Q = rq[w0] + rq[w0 + 1];
    float mu = S * (1.f / H);
    float var = Q * (1.f / H) - mu * mu;
    float y = (v - mu) * rsqrtf(var + LN_EPS) * G[j] + B[j];
    if (i < nN) {
        h[(size_t)i * H + j] = y;
        hb[(size_t)i * H + j] = f2b(y);
    }
}

__global__ void cast_kernel(const float* __restrict__ h, void* __restrict__ out,
                            int n, const int* __restrict__ flag) {
    int idx = blockIdx.x * blockDim.x + threadIdx.x;
    if (idx >= n) return;
    if (*flag) ((float*)out)[idx] = h[idx];
    else       ((hipbf16*)out)[idx] = __float2bfloat16(h[idx]);
}

extern "C" void kernel_launch(void* const* d_in, const int* in_sizes, int n_in,
                              void* d_out, int out_size, void* d_ws, size_t ws_size,
                              hipStream_t stream)
{
    const int* z  = (const int*)d_in[0];
    const int* ei = (const int*)d_in[2];

    const int nN = in_sizes[0];
    const int nE = in_sizes[2] / 2;
    const int* row = ei;
    const int* col = ei + nE;

    // ---- workspace layout (~77 MB total, proven safe) ----
    float* ws   = (float*)d_ws;
    int*   flag = (int*)ws;
    float* h    = ws + 64;
    unsigned short* hb = (unsigned short*)(h + (size_t)nN * H);
    float* agg  = (float*)(hb + (size_t)nN * H);
    float* conv = agg + (size_t)nN * H;

    const int n_pos = in_sizes[1];
    const int n_emb = in_sizes[3];
    const int n_ew1 = in_sizes[4], n_eb1 = in_sizes[5];
    const int n_ew2 = in_sizes[6], n_eb2 = in_sizes[7];
    const int n_nw1 = in_sizes[8], n_nb1 = in_sizes[9];
    const int n_nw2 = in_sizes[10], n_nb2 = in_sizes[11];
    const int n_lng = in_sizes[12], n_lnb = in_sizes[13];

    float* pos = conv;
    float* emb = pos + n_pos;
    float* ew1 = emb + n_emb;
    float* eb1 = ew1 + n_ew1;
    float* ew2 = eb1 + n_eb1;
    float* eb2 = ew2 + n_ew2;
    float* nw1 = eb2 + n_eb2;
    float* nb1 = nw1 + n_nw1;
    float* nw2 = nb1 + n_nb1;
    float* nb2 = nw2 + n_nw2;
    float* lng = nb2 + n_nb2;
    float* lnb = lng + n_lng;
    float* conv_end = lnb + n_lnb;

    unsigned short* pb1 = (unsigned short*)conv_end;          // 4 x 32768
    unsigned short* pb2 = pb1 + 4 * 32768;                    // 4 x 16384
    unsigned short* pn1 = pb2 + 4 * 16384;                    // 4 x 32768
    unsigned short* pn2 = pn1 + 4 * 32768;                    // 4 x 16384

    int* cnt   = (int*)(pn2 + 4 * 16384);
    int* rptr  = cnt + nN;
    int* cur   = rptr + nN + 1;
    int* rowsS = cur + nN;
    int* colsS = rowsS + nE;
    float* d2S = (float*)(colsS + nE);

    detect_kernel<<<1, 64, 0, stream>>>((const unsigned short*)d_in[4], 4096, flag);

    struct { const void* src; float* dst; int n; } cv[12] = {
        {d_in[1],  pos, n_pos}, {d_in[3],  emb, n_emb},
        {d_in[4],  ew1, n_ew1}, {d_in[5],  eb1, n_eb1},
        {d_in[6],  ew2, n_ew2}, {d_in[7],  eb2, n_eb2},
        {d_in[8],  nw1, n_nw1}, {d_in[9],  nb1, n_nb1},
        {d_in[10], nw2, n_nw2}, {d_in[11], nb2, n_nb2},
        {d_in[12], lng, n_lng}, {d_in[13], lnb, n_lnb},
    };
    for (int i = 0; i < 12; ++i)
        conv_kernel<<<(cv[i].n + 255) / 256, 256, 0, stream>>>(cv[i].src, cv[i].dst, cv[i].n, flag);

    for (int l = 0; l < NLAYERS; ++l) {
        pack_kernel<<<128, 256, 0, stream>>>(ew1 + (size_t)l * 257 * H, pb1 + l * 32768, 16);
        pack_kernel<<<64,  256, 0, stream>>>(ew2 + (size_t)l * H * H,   pb2 + l * 16384, 8);
        pack_kernel<<<128, 256, 0, stream>>>(nw1 + (size_t)l * 2 * H * H, pn1 + l * 32768, 16);
        pack_kernel<<<64,  256, 0, stream>>>(nw2 + (size_t)l * H * H,   pn2 + l * 16384, 8);
    }

    // CSR-order edges (counting sort by destination row)
    hipMemsetAsync(cnt, 0, (size_t)nN * sizeof(int), stream);
    hist_kernel<<<(nE + 255) / 256, 256, 0, stream>>>(row, cnt, nE);
    scan_kernel<<<1, 1024, 0, stream>>>(cnt, rptr, cur, nN);
    scatter_kernel<<<(nE + 255) / 256, 256, 0, stream>>>(row, col, pos, cur, rowsS, colsS, d2S, nE);

    embed_kernel<<<(nN * H + 255) / 256, 256, 0, stream>>>(z, emb, h, hb, nN);

    const int nTilesE = (nE + 127) / 128;
    const int nTilesN = (nN + 127) / 128;
    for (int l = 0; l < NLAYERS; ++l) {
        hipMemsetAsync(agg, 0, (size_t)nN * H * sizeof(float), stream);
        edge_wave<<<nTilesE, 256, 0, stream>>>(
            hb, rowsS, colsS, d2S,
            pb1 + l * 32768, eb1 + (size_t)l * H,
            ew1 + (size_t)l * 257 * H + 256 * H,
            pb2 + l * 16384, eb2 + (size_t)l * H,
            agg, nE);
        node_wave<<<nTilesN, 256, 0, stream>>>(
            hb, agg,
            pn1 + l * 32768, nb1 + (size_t)l * H,
            pn2 + l * 16384, nb2 + (size_t)l * H,
            agg /* hnew, overwritten in place */, nN);
        ln_kernel<<<(nN + 1) / 2, 256, 0, stream>>>(
            h, hb, agg, lng + (size_t)l * H, lnb + (size_t)l * H, nN);
    }
    cast_kernel<<<(nN * H + 255) / 256, 256, 0, stream>>>(h, d_out, nN * H, flag);
}

// Round 11
// 1487.784 us; speedup vs baseline: 1.0339x; 1.0339x over previous
//
#include <hip/hip_runtime.h>
#include <hip/hip_bf16.h>

typedef __hip_bfloat16 hipbf16;

#define H 128
#define NLAYERS 4
#define LN_EPS 1e-5f
#define ET 64           // edges/nodes per MFMA tile

typedef __bf16 bf16x8 __attribute__((ext_vector_type(8)));
typedef unsigned short ushort8 __attribute__((ext_vector_type(8)));
typedef float floatx16 __attribute__((ext_vector_type(16)));

union frag_u { ushort8 u; bf16x8 b; };

__device__ __forceinline__ float silu(float x) {
    return x * __builtin_amdgcn_rcpf(1.f + __expf(-x));
}
__device__ __forceinline__ float b2f_bits(unsigned short u) { return __uint_as_float(((unsigned)u) << 16); }
__device__ __forceinline__ unsigned short f2b(float f) {
    unsigned u = __float_as_uint(f);
    unsigned r = ((u >> 16) & 1u) + 0x7fffu;
    return (unsigned short)((u + r) >> 16);
}

// ---------------- dtype detection (wire fp32 vs bf16) ----------------
__global__ void detect_kernel(const unsigned short* __restrict__ p, int nHalf,
                              int* __restrict__ flag) {
    int t = threadIdx.x;
    int bad = 0;
    for (int i = t; i < nHalf; i += 64) {
        unsigned short u = p[i];
        int e = (u >> 7) & 0xFF;
        if (e >= 0x8E) bad = 1;
    }
    unsigned long long m = __ballot(bad != 0);
    if (t == 0) *flag = (m != 0ULL) ? 1 : 0;   // 1 => fp32 wire
}

__global__ void conv_kernel(const void* __restrict__ src, float* __restrict__ dst,
                            int n, const int* __restrict__ flag) {
    int i = blockIdx.x * blockDim.x + threadIdx.x;
    if (i >= n) return;
    if (*flag) dst[i] = ((const float*)src)[i];
    else       dst[i] = b2f_bits(((const unsigned short*)src)[i]);
}

// Pack W[K x 128] (fp32) into MFMA B-fragment order
__global__ void pack_kernel(const float* __restrict__ W, unsigned short* __restrict__ blob,
                            int ksteps) {
    int idx = blockIdx.x * 256 + threadIdx.x;
    if (idx >= ksteps * 2048) return;
    int j  = idx & 7;
    int L  = (idx >> 3) & 63;
    int nt = (idx >> 9) & 3;
    int ks = idx >> 11;
    int k = ks * 16 + (L >> 5) * 8 + j;
    int n = nt * 32 + (L & 31);
    blob[idx] = f2b(W[k * H + n]);
}

__global__ void embed_kernel(const int* __restrict__ z, const float* __restrict__ emb,
                             float* __restrict__ h, unsigned short* __restrict__ hb, int n) {
    int idx = blockIdx.x * blockDim.x + threadIdx.x;
    if (idx >= n * H) return;
    int i = idx >> 7, j = idx & 127;
    float v = emb[z[i] * H + j];
    h[idx] = v;
    hb[idx] = f2b(v);
}

// ---------------- CSR build (counting sort by destination row) ----------------
__global__ void hist_kernel(const int* __restrict__ row, int* __restrict__ cnt, int nE) {
    int i = blockIdx.x * blockDim.x + threadIdx.x;
    if (i < nE) atomicAdd(&cnt[row[i]], 1);
}

__global__ __launch_bounds__(1024) void scan_kernel(const int* __restrict__ cnt,
                                                    int* __restrict__ rptr,
                                                    int* __restrict__ cur, int nN) {
    __shared__ int wsum[17];
    __shared__ int s_carry;
    int t = threadIdx.x;
    if (t == 0) s_carry = 0;
    __syncthreads();
    for (int base = 0; base < nN; base += 1024) {
        int i = base + t;
        int v = (i < nN) ? cnt[i] : 0;
        int x = v;
        #pragma unroll
        for (int off = 1; off < 64; off <<= 1) {
            int y = __shfl_up(x, off);
            if ((t & 63) >= off) x += y;
        }
        if ((t & 63) == 63) wsum[t >> 6] = x;
        __syncthreads();
        if (t == 0) {
            int s = 0;
            #pragma unroll
            for (int w = 0; w < 16; ++w) { int tmp = wsum[w]; wsum[w] = s; s += tmp; }
            wsum[16] = s;
        }
        __syncthreads();
        int cin = s_carry;
        int excl = cin + wsum[t >> 6] + (x - v);
        if (i < nN) { rptr[i] = excl; cur[i] = excl; }
        __syncthreads();
        if (t == 0) s_carry = cin + wsum[16];
        __syncthreads();
    }
    if (t == 0) rptr[nN] = s_carry;
}

__global__ void scatter_kernel(const int* __restrict__ row, const int* __restrict__ col,
                               const float* __restrict__ pos,
                               int* __restrict__ cur,
                               int* __restrict__ rowsS, int* __restrict__ colsS,
                               float* __restrict__ d2S, int nE) {
    int e = blockIdx.x * blockDim.x + threadIdx.x;
    if (e >= nE) return;
    int r = row[e], c = col[e];
    int p = atomicAdd(&cur[r], 1);
    rowsS[p] = r;
    colsS[p] = c;
    float dx = pos[r * 3 + 0] - pos[c * 3 + 0];
    float dy = pos[r * 3 + 1] - pos[c * 3 + 1];
    float dz = pos[r * 3 + 2] - pos[c * 3 + 2];
    d2S[p] = dx * dx + dy * dy + dz * dz;
}

// ---------------- edge MLP: round-9 2x2 tiling, direct-global A, sT-only LDS --
// LDS = 17.4KB -> ~2x resident blocks vs round 9. One barrier. Per-lane edge
// ownership: lane lm of M-half wm owns edge p0+wm*32+lm (d2/tags via shfl).
__global__ __launch_bounds__(256) void edge_hyb(
    const unsigned short* __restrict__ hb,
    const int* __restrict__ rowsS, const int* __restrict__ colsS,
    const float* __restrict__ d2S,
    const unsigned short* __restrict__ pb1, const float* __restrict__ b1,
    const float* __restrict__ w1last,
    const unsigned short* __restrict__ pb2, const float* __restrict__ b2,
    float* __restrict__ agg, int nE)
{
    __shared__ __align__(16) unsigned short sT[ET * 136];   // 17408 B

    const int t = threadIdx.x;
    const int wv = t >> 6, lane = t & 63;
    const int wm = wv & 1, wn = wv >> 1;
    const int lm = lane & 31, lh = lane >> 5;
    const int n0 = wn * 64 + lm;
    const int p0 = blockIdx.x * ET;

    const int p = p0 + wm * 32 + lm;          // this lane's edge
    const bool valid = p < nE;
    const int pc = valid ? p : (nE - 1);
    const int nrow = rowsS[pc];
    const int ncol = colsS[pc];
    const float dd = d2S[pc];
    const int ptag = valid ? nrow : -1;

    const unsigned short* rowp = hb + (size_t)nrow * H + lh * 8;
    const unsigned short* colp = hb + (size_t)ncol * H + lh * 8;

    const float bias10 = b1[n0], bias11 = b1[n0 + 32];
    const float wl0 = w1last[n0], wl1 = w1last[n0 + 32];
    const float bias20 = b2[n0], bias21 = b2[n0 + 32];

    // GEMM1: [64,256] @ [256,128]; A-frag straight from global (k<128 row, else col)
    floatx16 acc0 = {}, acc1 = {};
    #pragma unroll
    for (int ks = 0; ks < 16; ++ks) {
        frag_u a, fb0, fb1;
        a.u = (ks < 8) ? *(const ushort8*)(rowp + ks * 16)
                       : *(const ushort8*)(colp + (ks - 8) * 16);
        fb0.u = *(const ushort8*)(pb1 + (size_t)((ks * 4 + wn * 2 + 0) * 64 + lane) * 8);
        fb1.u = *(const ushort8*)(pb1 + (size_t)((ks * 4 + wn * 2 + 1) * 64 + lane) * 8);
        acc0 = __builtin_amdgcn_mfma_f32_32x32x16_bf16(a.b, fb0.b, acc0, 0, 0, 0);
        acc1 = __builtin_amdgcn_mfma_f32_32x32x16_bf16(a.b, fb1.b, acc1, 0, 0, 0);
    }

    // epilogue 1: bias + d2*W1last (d2 via shfl), silu -> sT
    #pragma unroll
    for (int r = 0; r < 16; ++r) {
        int mi = (r & 3) + 8 * (r >> 2) + 4 * lh;      // m within half, [0,32)
        int m = wm * 32 + mi;
        float dm = __shfl(dd, mi);                     // lanes 0..31 hold this half's edges
        sT[m * 136 + n0]      = f2b(silu(acc0[r] + bias10 + dm * wl0));
        sT[m * 136 + n0 + 32] = f2b(silu(acc1[r] + bias11 + dm * wl1));
    }
    __syncthreads();

    // GEMM2: [64,128] @ [128,128]
    floatx16 c0 = {}, c1 = {};
    const unsigned short* A2 = sT + (wm * 32 + lm) * 136 + lh * 8;
    #pragma unroll
    for (int ks = 0; ks < 8; ++ks) {
        frag_u a, fb0, fb1;
        a.u   = *(const ushort8*)(A2 + ks * 16);
        fb0.u = *(const ushort8*)(pb2 + (size_t)((ks * 4 + wn * 2 + 0) * 64 + lane) * 8);
        fb1.u = *(const ushort8*)(pb2 + (size_t)((ks * 4 + wn * 2 + 1) * 64 + lane) * 8);
        c0 = __builtin_amdgcn_mfma_f32_32x32x16_bf16(a.b, fb0.b, c0, 0, 0, 0);
        c1 = __builtin_amdgcn_mfma_f32_32x32x16_bf16(a.b, fb1.b, c1, 0, 0, 0);
    }

    // epilogue 2: silu + register run-compaction (tags via shfl)
    #pragma unroll
    for (int g = 0; g < 4; ++g) {
        const int mi0 = 4 * lh + 8 * g;
        int prow = __shfl(ptag, mi0);
        float s0 = silu(c0[g * 4] + bias20);
        float s1 = silu(c1[g * 4] + bias21);
        #pragma unroll
        for (int k = 1; k < 4; ++k) {
            int rw = __shfl(ptag, mi0 + k);
            float u0 = silu(c0[g * 4 + k] + bias20);
            float u1 = silu(c1[g * 4 + k] + bias21);
            if (rw == prow) {
                s0 += u0; s1 += u1;
            } else {
                if (prow >= 0) {
                    atomicAdd(&agg[(size_t)prow * H + n0],      s0);
                    atomicAdd(&agg[(size_t)prow * H + n0 + 32], s1);
                }
                prow = rw; s0 = u0; s1 = u1;
            }
        }
        if (prow >= 0) {
            atomicAdd(&agg[(size_t)prow * H + n0],      s0);
            atomicAdd(&agg[(size_t)prow * H + n0 + 32], s1);
        }
    }
}

// ---------------- node MLP: same hybrid structure ----------------
__global__ __launch_bounds__(256) void node_hyb(
    const unsigned short* __restrict__ hb,
    const float* __restrict__ aggf,
    const unsigned short* __restrict__ pn1, const float* __restrict__ b1,
    const unsigned short* __restrict__ pn2, const float* __restrict__ b2,
    float* __restrict__ hnew, int nN)
{
    __shared__ __align__(16) unsigned short sT[ET * 136];

    const int t = threadIdx.x;
    const int wv = t >> 6, lane = t & 63;
    const int wm = wv & 1, wn = wv >> 1;
    const int lm = lane & 31, lh = lane >> 5;
    const int n0 = wn * 64 + lm;
    const int i0 = blockIdx.x * ET;

    const int node = min(i0 + wm * 32 + lm, nN - 1);
    const unsigned short* hp = hb + (size_t)node * H + lh * 8;
    const float* ap = aggf + (size_t)node * H + lh * 8;

    floatx16 acc0 = {}, acc1 = {};
    #pragma unroll
    for (int ks = 0; ks < 16; ++ks) {
        frag_u a;
        if (ks < 8) {
            a.u = *(const ushort8*)(hp + ks * 16);
        } else {
            float4 x = *(const float4*)(ap + (ks - 8) * 16);
            float4 y = *(const float4*)(ap + (ks - 8) * 16 + 4);
            a.u[0] = f2b(x.x); a.u[1] = f2b(x.y); a.u[2] = f2b(x.z); a.u[3] = f2b(x.w);
            a.u[4] = f2b(y.x); a.u[5] = f2b(y.y); a.u[6] = f2b(y.z); a.u[7] = f2b(y.w);
        }
        frag_u fb0, fb1;
        fb0.u = *(const ushort8*)(pn1 + (size_t)((ks * 4 + wn * 2 + 0) * 64 + lane) * 8);
        fb1.u = *(const ushort8*)(pn1 + (size_t)((ks * 4 + wn * 2 + 1) * 64 + lane) * 8);
        acc0 = __builtin_amdgcn_mfma_f32_32x32x16_bf16(a.b, fb0.b, acc0, 0, 0, 0);
        acc1 = __builtin_amdgcn_mfma_f32_32x32x16_bf16(a.b, fb1.b, acc1, 0, 0, 0);
    }

    {
        float bias0 = b1[n0], bias1 = b1[n0 + 32];
        #pragma unroll
        for (int r = 0; r < 16; ++r) {
            int m = wm * 32 + (r & 3) + 8 * (r >> 2) + 4 * lh;
            sT[m * 136 + n0]      = f2b(silu(acc0[r] + bias0));
            sT[m * 136 + n0 + 32] = f2b(silu(acc1[r] + bias1));
        }
    }
    __syncthreads();

    floatx16 c0 = {}, c1 = {};
    const unsigned short* A2 = sT + (wm * 32 + lm) * 136 + lh * 8;
    #pragma unroll
    for (int ks = 0; ks < 8; ++ks) {
        frag_u a, fb0, fb1;
        a.u   = *(const ushort8*)(A2 + ks * 16);
        fb0.u = *(const ushort8*)(pn2 + (size_t)((ks * 4 + wn * 2 + 0) * 64 + lane) * 8);
        fb1.u = *(const ushort8*)(pn2 + (size_t)((ks * 4 + wn * 2 + 1) * 64 + lane) * 8);
        c0 = __builtin_amdgcn_mfma_f32_32x32x16_bf16(a.b, fb0.b, c0, 0, 0, 0);
        c1 = __builtin_amdgcn_mfma_f32_32x32x16_bf16(a.b, fb1.b, c1, 0, 0, 0);
    }
    {
        float bias0 = b2[n0], bias1 = b2[n0 + 32];
        #pragma unroll
        for (int r = 0; r < 16; ++r) {
            int m = wm * 32 + (r & 3) + 8 * (r >> 2) + 4 * lh;
            int nd = i0 + m;
            if (nd < nN) {
                float* dst = hnew + (size_t)nd * H;
                dst[n0]      = c0[r] + bias0;
                dst[n0 + 32] = c1[r] + bias1;
            }
        }
    }
}

// residual + layernorm; writes fp32 h and bf16 mirror
__global__ __launch_bounds__(256) void ln_kernel(
    float* __restrict__ h, unsigned short* __restrict__ hb,
    const float* __restrict__ hnew,
    const float* __restrict__ G, const float* __restrict__ B, int nN)
{
    __shared__ float rs[4], rq[4];
    int t = threadIdx.x;
    int local = t >> 7, j = t & 127;
    int i = blockIdx.x * 2 + local;
    float v = 0.f;
    if (i < nN) v = h[(size_t)i * H + j] + hnew[(size_t)i * H + j];
    float s = v, q = v * v;
    #pragma unroll
    for (int off = 32; off > 0; off >>= 1) {
        s += __shfl_down(s, off);
        q += __shfl_down(q, off);
    }
    int w = t >> 6;
    if ((t & 63) == 0) { rs[w] = s; rq[w] = q; }
    __syncthreads();
    int w0 = local * 2;
    float S = rs[w0] + rs[w0 + 1], Q = rq[w0] + rq[w0 + 1];
    float mu = S * (1.f / H);
    float var = Q * (1.f / H) - mu * mu;
    float y = (v - mu) * rsqrtf(var + LN_EPS) * G[j] + B[j];
    if (i < nN) {
        h[(size_t)i * H + j] = y;
        hb[(size_t)i * H + j] = f2b(y);
    }
}

__global__ void cast_kernel(const float* __restrict__ h, void* __restrict__ out,
                            int n, const int* __restrict__ flag) {
    int idx = blockIdx.x * blockDim.x + threadIdx.x;
    if (idx >= n) return;
    if (*flag) ((float*)out)[idx] = h[idx];
    else       ((hipbf16*)out)[idx] = __float2bfloat16(h[idx]);
}

extern "C" void kernel_launch(void* const* d_in, const int* in_sizes, int n_in,
                              void* d_out, int out_size, void* d_ws, size_t ws_size,
                              hipStream_t stream)
{
    const int* z  = (const int*)d_in[0];
    const int* ei = (const int*)d_in[2];

    const int nN = in_sizes[0];
    const int nE = in_sizes[2] / 2;
    const int* row = ei;
    const int* col = ei + nE;

    // ---- workspace layout (~77 MB total, proven safe) ----
    float* ws   = (float*)d_ws;
    int*   flag = (int*)ws;
    float* h    = ws + 64;
    unsigned short* hb = (unsigned short*)(h + (size_t)nN * H);
    float* agg  = (float*)(hb + (size_t)nN * H);
    float* conv = agg + (size_t)nN * H;

    const int n_pos = in_sizes[1];
    const int n_emb = in_sizes[3];
    const int n_ew1 = in_sizes[4], n_eb1 = in_sizes[5];
    const int n_ew2 = in_sizes[6], n_eb2 = in_sizes[7];
    const int n_nw1 = in_sizes[8], n_nb1 = in_sizes[9];
    const int n_nw2 = in_sizes[10], n_nb2 = in_sizes[11];
    const int n_lng = in_sizes[12], n_lnb = in_sizes[13];

    float* pos = conv;
    float* emb = pos + n_pos;
    float* ew1 = emb + n_emb;
    float* eb1 = ew1 + n_ew1;
    float* ew2 = eb1 + n_eb1;
    float* eb2 = ew2 + n_ew2;
    float* nw1 = eb2 + n_eb2;
    float* nb1 = nw1 + n_nw1;
    float* nw2 = nb1 + n_nb1;
    float* nb2 = nw2 + n_nw2;
    float* lng = nb2 + n_nb2;
    float* lnb = lng + n_lng;
    float* conv_end = lnb + n_lnb;

    unsigned short* pb1 = (unsigned short*)conv_end;          // 4 x 32768
    unsigned short* pb2 = pb1 + 4 * 32768;                    // 4 x 16384
    unsigned short* pn1 = pb2 + 4 * 16384;                    // 4 x 32768
    unsigned short* pn2 = pn1 + 4 * 32768;                    // 4 x 16384

    int* cnt   = (int*)(pn2 + 4 * 16384);
    int* rptr  = cnt + nN;
    int* cur   = rptr + nN + 1;
    int* rowsS = cur + nN;
    int* colsS = rowsS + nE;
    float* d2S = (float*)(colsS + nE);

    detect_kernel<<<1, 64, 0, stream>>>((const unsigned short*)d_in[4], 4096, flag);

    struct { const void* src; float* dst; int n; } cv[12] = {
        {d_in[1],  pos, n_pos}, {d_in[3],  emb, n_emb},
        {d_in[4],  ew1, n_ew1}, {d_in[5],  eb1, n_eb1},
        {d_in[6],  ew2, n_ew2}, {d_in[7],  eb2, n_eb2},
        {d_in[8],  nw1, n_nw1}, {d_in[9],  nb1, n_nb1},
        {d_in[10], nw2, n_nw2}, {d_in[11], nb2, n_nb2},
        {d_in[12], lng, n_lng}, {d_in[13], lnb, n_lnb},
    };
    for (int i = 0; i < 12; ++i)
        conv_kernel<<<(cv[i].n + 255) / 256, 256, 0, stream>>>(cv[i].src, cv[i].dst, cv[i].n, flag);

    for (int l = 0; l < NLAYERS; ++l) {
        pack_kernel<<<128, 256, 0, stream>>>(ew1 + (size_t)l * 257 * H, pb1 + l * 32768, 16);
        pack_kernel<<<64,  256, 0, stream>>>(ew2 + (size_t)l * H * H,   pb2 + l * 16384, 8);
        pack_kernel<<<128, 256, 0, stream>>>(nw1 + (size_t)l * 2 * H * H, pn1 + l * 32768, 16);
        pack_kernel<<<64,  256, 0, stream>>>(nw2 + (size_t)l * H * H,   pn2 + l * 16384, 8);
    }

    // CSR-order edges (counting sort by destination row)
    hipMemsetAsync(cnt, 0, (size_t)nN * sizeof(int), stream);
    hist_kernel<<<(nE + 255) / 256, 256, 0, stream>>>(row, cnt, nE);
    scan_kernel<<<1, 1024, 0, stream>>>(cnt, rptr, cur, nN);
    scatter_kernel<<<(nE + 255) / 256, 256, 0, stream>>>(row, col, pos, cur, rowsS, colsS, d2S, nE);

    embed_kernel<<<(nN * H + 255) / 256, 256, 0, stream>>>(z, emb, h, hb, nN);

    const int nTiles = (nE + ET - 1) / ET;
    const int nTilesN = (nN + ET - 1) / ET;
    for (int l = 0; l < NLAYERS; ++l) {
        hipMemsetAsync(agg, 0, (size_t)nN * H * sizeof(float), stream);
        edge_hyb<<<nTiles, 256, 0, stream>>>(
            hb, rowsS, colsS, d2S,
            pb1 + l * 32768, eb1 + (size_t)l * H,
            ew1 + (size_t)l * 257 * H + 256 * H,
            pb2 + l * 16384, eb2 + (size_t)l * H,
            agg, nE);
        node_hyb<<<nTilesN, 256, 0, stream>>>(
            hb, agg,
            pn1 + l * 32768, nb1 + (size_t)l * H,
            pn2 + l * 16384, nb2 + (size_t)l * H,
            agg /* hnew, overwritten in place */, nN);
        ln_kernel<<<(nN + 1) / 2, 256, 0, stream>>>(
            h, hb, agg, lng + (size_t)l * H, lnb + (size_t)l * H, nN);
    }
    cast_kernel<<<(nN * H + 255) / 256, 256, 0, stream>>>(h, d_out, nN * H, flag);
}